// Round 10
// baseline (333.697 us; speedup 1.0000x reference)
//
#include <hip/hip_runtime.h>
#include <hip/hip_bf16.h>

// MultiheadAttention: x[4,2048,1024] fp32 -> out fp32. Internal bf16 MFMA.
// R10: (1) qkv_gemm 256x128 tile (8 waves) — staging traffic 786->590 MB,
// 2x MFMA per A-byte; (2) z=2 (V^T) epilogue via per-wave LDS transpose ->
// coalesced dwordx4 stores (was 8B/lane @4KB stride, ~8x amplification);
// (3) attn rsum via ones-row mfma16 (kills 16 v_add/iter + post shuffles).

#define DIM  1024
#define SEQ  2048
#define BATCH 4
#define NH   16
#define HD   64

typedef __bf16 bf16x8 __attribute__((ext_vector_type(8)));
typedef short  s16x4  __attribute__((ext_vector_type(4)));
typedef float  f32x4  __attribute__((ext_vector_type(4)));
typedef unsigned int uint4v __attribute__((ext_vector_type(4)));

static __device__ __forceinline__ f32x4 mfma16(s16x4 a, s16x4 b, f32x4 c) {
    return __builtin_amdgcn_mfma_f32_16x16x16bf16_1k(a, b, c, 0, 0, 0);
}

static __device__ __forceinline__ unsigned short f2b(float f) {
    __bf16 h = (__bf16)f;                      // RNE convert
    return __builtin_bit_cast(unsigned short, h);
}

static __device__ __forceinline__ void load_lds16(const unsigned short* g,
                                                  unsigned short* l) {
    __builtin_amdgcn_global_load_lds(
        (const __attribute__((address_space(1))) void*)g,
        (__attribute__((address_space(3))) void*)l, 16, 0, 0);
}

// ---------------------------------------------------------------------------
// Kernel A: x fp32 -> bf16. 8,388,608 elems -> 4096 blocks.
// ---------------------------------------------------------------------------
__global__ __launch_bounds__(256) void cvt_x_k(const float* __restrict__ x,
                                               unsigned short* __restrict__ xb) {
    size_t i = ((size_t)blockIdx.x * 256 + threadIdx.x) * 8;
    const f32x4* s = (const f32x4*)(x + i);
    f32x4 a0 = s[0], a1 = s[1];
    bf16x8 v;
    for (int j = 0; j < 4; j++) { v[j] = (__bf16)a0[j]; v[4 + j] = (__bf16)a1[j]; }
    *(bf16x8*)(xb + i) = v;
}

// ---------------------------------------------------------------------------
// Kernel 0: Wt[n][k] = bf16(W[k][n]) for z = 0,1,2 (Wq,Wk,Wv). fp32 input.
// ---------------------------------------------------------------------------
__global__ void transpose_w_k(const float* __restrict__ Wq,
                              const float* __restrict__ Wk,
                              const float* __restrict__ Wv,
                              unsigned short* __restrict__ Wt) {
    __shared__ unsigned short t[32][33];
    int z = blockIdx.z;
    const float* W = (z == 0) ? Wq : (z == 1) ? Wk : Wv;
    unsigned short* o = Wt + (size_t)z * DIM * DIM;
    int tx = threadIdx.x;
    int n0 = blockIdx.x * 32, k0 = blockIdx.y * 32;
    for (int j = threadIdx.y; j < 32; j += 8)
        t[j][tx] = f2b(W[(size_t)(k0 + j) * DIM + n0 + tx]);
    __syncthreads();
    for (int j = threadIdx.y; j < 32; j += 8)
        o[(size_t)(n0 + j) * DIM + k0 + tx] = t[tx][j];
}

// ---------------------------------------------------------------------------
// Kernel 1: fused QKV projection. grid (8, 32, 3), block 512 (8 waves).
// 256x128 tile, BK=32. global_load_lds staging, XOR swizzle (R9-verified).
// z=0 -> Q scaled log2e/8, z=1 -> K, z=2 -> V^T via per-wave LDS transpose.
// ---------------------------------------------------------------------------
__global__ __launch_bounds__(512) void qkv_gemm_k(
    const unsigned short* __restrict__ xb,
    const unsigned short* __restrict__ WtBase,
    const float* __restrict__ bq,
    const float* __restrict__ bk,
    const float* __restrict__ bv,
    unsigned short* __restrict__ Qo,
    unsigned short* __restrict__ Ko,
    unsigned short* __restrict__ Vto) {
    __shared__ __align__(16) unsigned short As[256 * 32];   // 16 KB, NO pad
    __shared__ __align__(16) unsigned short Bs[128 * 32];   // 8 KB
    int tid = threadIdx.x, wave = tid >> 6, lane = tid & 63;
    int quad = lane >> 4, lc = lane & 15;
    int m0 = blockIdx.y * 256, n0 = blockIdx.x * 128;
    int z = blockIdx.z;
    const unsigned short* Wt = WtBase + (size_t)z * DIM * DIM;
    int wm = (wave >> 1) * 64, wn = (wave & 1) * 64;

    // staging: A rows 0..255 (2 chunks/thread), B rows 0..127 (1 chunk/thread)
    int cA0 = tid, rA0 = cA0 >> 2, xA0 = ((cA0 & 3) ^ ((rA0 >> 1) & 3)) * 8;
    int cA1 = tid + 512, rA1 = cA1 >> 2, xA1 = ((cA1 & 3) ^ ((rA1 >> 1) & 3)) * 8;
    int rB = tid >> 2, xB = ((tid & 3) ^ ((rB >> 1) & 3)) * 8;
    const unsigned short* gA0 = xb + (size_t)(m0 + rA0) * DIM + xA0;
    const unsigned short* gA1 = xb + (size_t)(m0 + rA1) * DIM + xA1;
    const unsigned short* gB  = Wt + (size_t)(n0 + rB) * DIM + xB;

    int swz = (quad ^ ((lc >> 1) & 3)) * 8;   // frag-read swizzle (lc-only)

    f32x4 acc[4][4] = {};

    for (int k0 = 0; k0 < DIM; k0 += 32) {
        __syncthreads();
        load_lds16(gA0 + k0, &As[cA0 * 8]);
        load_lds16(gA1 + k0, &As[cA1 * 8]);
        load_lds16(gB + k0, &Bs[tid * 8]);
        __syncthreads();
        bf16x8 af[4], bfr[4];
        for (int mt = 0; mt < 4; mt++)
            af[mt] = *(const bf16x8*)&As[(wm + mt * 16 + lc) * 32 + swz];
        for (int nt = 0; nt < 4; nt++)
            bfr[nt] = *(const bf16x8*)&Bs[(wn + nt * 16 + lc) * 32 + swz];
        for (int mt = 0; mt < 4; mt++)
            for (int nt = 0; nt < 4; nt++)
                acc[mt][nt] = __builtin_amdgcn_mfma_f32_16x16x32_bf16(
                    af[mt], bfr[nt], acc[mt][nt], 0, 0, 0);
    }

    const float* bias = (z == 0) ? bq : (z == 1) ? bk : bv;
    float scale = (z == 0) ? 0.18033688011112042f : 1.0f;  // (1/8)*log2(e)

    if (z != 2) {
        for (int nt = 0; nt < 4; nt++) {
            int n = n0 + wn + nt * 16 + lc;
            float bvl = bias[n];
            int h = n >> 6, d = n & 63;
            for (int mt = 0; mt < 4; mt++) {
                for (int r = 0; r < 4; r++) {
                    int m = m0 + wm + mt * 16 + quad * 4 + r;
                    int b = m >> 11, s = m & 2047;
                    unsigned short ub = f2b((acc[mt][nt][r] + bvl) * scale);
                    if (z == 0)
                        Qo[((size_t)(b * NH + h) * SEQ + s) * HD + d] = ub;
                    else
                        Ko[((size_t)(b * NH + h) * SEQ + s) * HD + d] = ub;
                }
            }
        }
    } else {
        // V^T: per-wave LDS transpose (16 m x 64 n slices), coalesced stores.
        __syncthreads();  // all waves done reading As/Bs
        unsigned short* T = As + wave * 1024;   // 64 n-rows x 16 m, 2 KB/wave
        int h = (n0 + wn) >> 6;                 // 64-aligned, single head/wave
        int d = lane;                           // 0..63 within head
        for (int mt = 0; mt < 4; mt++) {
            for (int nt = 0; nt < 4; nt++) {
                int n = n0 + wn + nt * 16 + lc;
                float bvl = bias[n];
                s16x4 v4;
                for (int r = 0; r < 4; r++)
                    v4[r] = (short)f2b(acc[mt][nt][r] + bvl);
                *(s16x4*)&T[(nt * 16 + lc) * 16 + quad * 4] = v4;  // ds_write_b64
            }
            // wave-private region: compiler lgkmcnt covers write->read dep
            int s_base = m0 + wm + mt * 16;
            int b = s_base >> 11, sl = s_base & 2047;
            unsigned short* dst =
                Vto + ((size_t)(b * NH + h) * HD + d) * SEQ + sl;
            uint4v t0 = *(const uint4v*)&T[d * 16];
            uint4v t1 = *(const uint4v*)&T[d * 16 + 8];
            *(uint4v*)&dst[0] = t0;
            *(uint4v*)&dst[8] = t1;
        }
    }
}

// ---------------------------------------------------------------------------
// Kernel 2: flash attention v5 (t-split; rsum via ones-MFMA). grid (32,16,4).
// ---------------------------------------------------------------------------
__global__ __launch_bounds__(256) void attn_k(
    const unsigned short* __restrict__ Q,
    const unsigned short* __restrict__ K,
    const unsigned short* __restrict__ Vt,
    float* __restrict__ out) {
    constexpr int LD = 72;   // bf16 tiles: 64 + 8 pad, rows 144B
    __shared__ __align__(16) unsigned short KV[2 * 64 * LD];  // 18432 B
    unsigned short* Ks = KV;
    unsigned short* Vs = KV + 64 * LD;

    int tid = threadIdx.x, wave = tid >> 6, lane = tid & 63;
    int quad = lane >> 4, lc = lane & 15;
    int w16 = wave * 16;
    int b = blockIdx.z, h = blockIdx.y, qt = blockIdx.x;
    int bh = b * NH + h;
    const unsigned short* Qg = Q + ((size_t)bh * SEQ + qt * 64) * HD;
    const unsigned short* Kg = K + (size_t)bh * SEQ * HD;
    const unsigned short* Vg = Vt + (size_t)bh * HD * SEQ;

    for (int p = 0; p < 2; p++) {
        int c = tid + p * 256;
        int row = c >> 3, cc = c & 7;
        *(uint4v*)&Ks[row * LD + cc * 8] = *(const uint4v*)&Qg[c * 8];
    }
    __syncthreads();
    bf16x8 qf[4][2];  // [q-group g][ks]: B[k=d=ks*32+quad*8+j][n=q=g*16+lc]
    #pragma unroll
    for (int g = 0; g < 4; g++)
        #pragma unroll
        for (int ks = 0; ks < 2; ks++)
            qf[g][ks] = *(const bf16x8*)&Ks[(g * 16 + lc) * LD + ks * 32 + quad * 8];

    f32x4 o[4][4] = {};   // [dt][g]: O^T[d=dt*16+quad*4+r][q=g*16+lc]
    f32x4 ors[4] = {};    // [g]: rows all = sum_t P (ones-row trick)
    s16x4 onesv;
    onesv[0] = onesv[1] = onesv[2] = onesv[3] = (short)0x3F80;  // bf16 1.0

    for (int t0 = 0; t0 < SEQ; t0 += 64) {
        __syncthreads();
        for (int p = 0; p < 2; p++) {
            int c = tid + p * 256;
            int row = c >> 3, cc = c & 7;
            *(uint4v*)&Ks[row * LD + cc * 8] =
                *(const uint4v*)&Kg[(size_t)t0 * HD + c * 8];
            *(uint4v*)&Vs[row * LD + cc * 8] =
                *(const uint4v*)&Vg[(size_t)row * SEQ + t0 + cc * 8];
        }
        __syncthreads();

        f32x4 sc[4] = {};
        #pragma unroll
        for (int ks = 0; ks < 2; ks++) {
            bf16x8 kf = *(const bf16x8*)&Ks[(w16 + lc) * LD + ks * 32 + quad * 8];
            #pragma unroll
            for (int g = 0; g < 4; g++)
                sc[g] = __builtin_amdgcn_mfma_f32_16x16x32_bf16(kf, qf[g][ks], sc[g], 0, 0, 0);
        }

        s16x4 pf[4];
        #pragma unroll
        for (int g = 0; g < 4; g++) {
            float p0 = __builtin_amdgcn_exp2f(sc[g][0]);
            float p1 = __builtin_amdgcn_exp2f(sc[g][1]);
            float p2 = __builtin_amdgcn_exp2f(sc[g][2]);
            float p3 = __builtin_amdgcn_exp2f(sc[g][3]);
            pf[g][0] = (short)f2b(p0); pf[g][1] = (short)f2b(p1);
            pf[g][2] = (short)f2b(p2); pf[g][3] = (short)f2b(p3);
            ors[g] = mfma16(onesv, pf[g], ors[g]);   // rsum rows (k spans quads)
        }

        #pragma unroll
        for (int dt = 0; dt < 4; dt++) {
            s16x4 vf = *(const s16x4*)&Vs[(dt * 16 + lc) * LD + w16 + quad * 4];
            #pragma unroll
            for (int g = 0; g < 4; g++)
                o[dt][g] = mfma16(vf, pf[g], o[dt][g]);
        }
    }

    __syncthreads();
    float* OredF = (float*)KV;            // [4w][64q][16dd] = 16384 B
    float* rsArr = (float*)KV + 4096;     // [4w][64q] = 1024 B
    if (lane < 16)
        #pragma unroll
        for (int g = 0; g < 4; g++)
            rsArr[wave * 64 + g * 16 + lane] = ors[g][0];  // wave-full sum

    int q = tid >> 2, cs = tid & 3;
    float inv = 0.0f;
    float* orow = out + ((size_t)b * SEQ + qt * 64 + q) * DIM + h * HD;
    #pragma unroll
    for (int dt = 0; dt < 4; dt++) {
        #pragma unroll
        for (int g = 0; g < 4; g++)
            *(f32x4*)&OredF[wave * 1024 + (g * 16 + lc) * 16 + quad * 4] = o[dt][g];
        __syncthreads();
        if (dt == 0)
            inv = 1.0f / (rsArr[q] + rsArr[64 + q] + rsArr[128 + q] + rsArr[192 + q]);
        f32x4 s = *(const f32x4*)&OredF[q * 16 + cs * 4];
        #pragma unroll
        for (int w = 1; w < 4; w++)
            s += *(const f32x4*)&OredF[w * 1024 + q * 16 + cs * 4];
        s *= inv;
        *(f32x4*)&orow[dt * 16 + cs * 4] = s;
        __syncthreads();
    }
}

// ---------------------------------------------------------------------------
extern "C" void kernel_launch(void* const* d_in, const int* in_sizes, int n_in,
                              void* d_out, int out_size, void* d_ws, size_t ws_size,
                              hipStream_t stream) {
    (void)in_sizes; (void)n_in; (void)out_size; (void)ws_size;
    const float* x  = (const float*)d_in[0];
    const float* Wq = (const float*)d_in[1];
    const float* bq = (const float*)d_in[2];
    const float* Wk = (const float*)d_in[3];
    const float* bk = (const float*)d_in[4];
    const float* Wv = (const float*)d_in[5];
    const float* bv = (const float*)d_in[6];

    char* ws = (char*)d_ws;
    unsigned short* Wt = (unsigned short*)ws;                             // 6 MB
    unsigned short* Qb = (unsigned short*)(ws + (size_t)6 * 1024 * 1024);
    unsigned short* Kb = Qb + (size_t)BATCH * NH * SEQ * HD;
    unsigned short* Vb = Kb + (size_t)BATCH * NH * SEQ * HD;
    unsigned short* xb = (unsigned short*)d_out;  // scratch; attn overwrites

    cvt_x_k<<<dim3(4096), dim3(256), 0, stream>>>(x, xb);
    transpose_w_k<<<dim3(32, 32, 3), dim3(32, 8), 0, stream>>>(Wq, Wk, Wv, Wt);
    qkv_gemm_k<<<dim3(8, 32, 3), dim3(512), 0, stream>>>(xb, Wt, bq, bk, bv, Qb, Kb, Vb);
    attn_k<<<dim3(32, NH, BATCH), dim3(256), 0, stream>>>(Qb, Kb, Vb, (float*)d_out);
}